// Round 7
// baseline (59.258 us; speedup 1.0000x reference)
//
#include <hip/hip_runtime.h>

// Problem constants (fixed by the reference).
constexpr int kN = 2048;
constexpr int kB = 16;
constexpr int kNB = 128;  // NUM_BUCKETS
constexpr int kR = 4;     // rows per block (divides kN -> no batch crossing)

// fl32(ln2) = 0x3F317218 — what any f32 log chain divides by (log(2.0f)).
#define LN2_BITS 0x3f317218u

// Native vector types (HIP's float4/int4 are classes; nontemporal builtin
// needs a true vector type).
typedef float f32x4 __attribute__((ext_vector_type(4)));
typedef int   i32x4 __attribute__((ext_vector_type(4)));

// ---------------------------------------------------------------------------
// Bucket matching the all-f32 arbiter chain with correctly-rounded f32 log
// (verified absmax 0.0 in R3/R5/R6 — DO NOT TOUCH):
//   bk = clip( floorf( fl32( CRlog32(a) / fl32(ln2) ) ), 0, 128 ), a = max(|dt|,1)
// Fast path 31-clz(a) is provably identical outside narrow windows around 2^j;
// inside, emulate with (float)log((double)a) + IEEE f32 divide.
// ---------------------------------------------------------------------------
__device__ __forceinline__ int bucket_of(int rowts, int tj) {
    int dt = rowts - tj;
    unsigned a = (unsigned)(dt < 0 ? -dt : dt);
    a = a < 1u ? 1u : a;                   // a in [1, 10^7) < 2^24
    int k = 31 - __clz((int)a);            // exact floor(log2(a))
    unsigned p = 1u << k;
    unsigned Wlo = ((p >> 20) * (unsigned)k) + 8u;
    unsigned Whi = ((p >> 19) * (unsigned)(k + 1)) + 8u;
    bool danger = ((a - p) < Wlo) | (((p << 1) - a) < Whi);
    if (!danger) return k;
    float L = (float)log((double)a);       // correctly-rounded f32 log(a)
    float q = L / __uint_as_float(LN2_BITS);  // IEEE f32 divide (no fast-math)
    int bk = (int)floorf(q);
    return bk < 0 ? 0 : (bk > kNB ? kNB : bk);
}

// ---------------------------------------------------------------------------
// Fused kernel, kR rows per block, ROW-LINEAR store order (r outer, kk inner):
// each block writes its kR rows as sequential linear 8 KB streams — same DRAM
// access shape as the 7 TB/s fill kernel — while still amortizing the ts_w
// stage and reusing the column int4 loads (t4a/t4b live in registers).
// Output is write-once and bigger than L3 -> nontemporal stores.
// ---------------------------------------------------------------------------
__global__ __launch_bounds__(256) void bias_kernel(const int* __restrict__ ts,
                                                   const float* __restrict__ pos_w,
                                                   const float* __restrict__ ts_w,
                                                   float* __restrict__ out) {
    const int blk = blockIdx.x;
    constexpr int kTsBlocks = kB * kN / kR;   // 8192

    if (blk < kTsBlocks) {
        // ---- bucketized timestamp bias rows [blk*kR, blk*kR + kR) ----
        __shared__ float w[kNB + 1];
        if (threadIdx.x <= kNB) w[threadIdx.x] = ts_w[threadIdx.x];
        __syncthreads();

        const int row0 = blk * kR;              // global ts-row index b*kN + i0
        const int b    = row0 >> 11;            // / kN
        const int i0   = row0 & (kN - 1);
        const int* __restrict__ tsrow = ts + (size_t)b * kN;

        int rowts[kR];
        #pragma unroll
        for (int r = 0; r < kR; ++r)
            rowts[r] = tsrow[min(i0 + r + 1, kN - 1)];

        const i32x4* __restrict__ ts4 = (const i32x4*)tsrow;
        const i32x4 t4a = ts4[threadIdx.x];          // column loads: once per
        const i32x4 t4b = ts4[256 + threadIdx.x];    // block, reused kR times

        f32x4* __restrict__ obase4 =
            (f32x4*)(out + (size_t)kN * kN + (size_t)row0 * kN);

        #pragma unroll
        for (int r = 0; r < kR; ++r) {
            const int rt = rowts[r];
            f32x4 res;
            res.x = w[bucket_of(rt, t4a.x)];
            res.y = w[bucket_of(rt, t4a.y)];
            res.z = w[bucket_of(rt, t4a.z)];
            res.w = w[bucket_of(rt, t4a.w)];
            __builtin_nontemporal_store(res, &obase4[r * (kN / 4) + threadIdx.x]);
            res.x = w[bucket_of(rt, t4b.x)];
            res.y = w[bucket_of(rt, t4b.y)];
            res.z = w[bucket_of(rt, t4b.z)];
            res.w = w[bucket_of(rt, t4b.w)];
            __builtin_nontemporal_store(res,
                &obase4[r * (kN / 4) + 256 + threadIdx.x]);
        }
    } else {
        // ---- relative position bias rows: out[i][j] = pos_w[N-1-i + j] ----
        const int i0 = (blk - kTsBlocks) * kR;
        #pragma unroll
        for (int r = 0; r < kR; ++r) {
            const float* __restrict__ src = pos_w + (kN - 1 - (i0 + r));
            f32x4* __restrict__ orow4 = (f32x4*)(out + (size_t)(i0 + r) * kN);
            #pragma unroll
            for (int kk = 0; kk < 2; ++kk) {
                const int v = kk * 256 + threadIdx.x;
                f32x4 res;
                res.x = src[4 * v + 0];
                res.y = src[4 * v + 1];
                res.z = src[4 * v + 2];
                res.w = src[4 * v + 3];
                __builtin_nontemporal_store(res, &orow4[v]);
            }
        }
    }
}

extern "C" void kernel_launch(void* const* d_in, const int* in_sizes, int n_in,
                              void* d_out, int out_size, void* d_ws, size_t ws_size,
                              hipStream_t stream) {
    const int*   all_ts = (const int*)d_in[0];    // (B, N) int32
    const float* pos_w  = (const float*)d_in[1];  // (2N-1,) f32
    const float* ts_w   = (const float*)d_in[2];  // (NB+1,) f32
    float* out = (float*)d_out;                   // [N*N] pos ++ [B*N*N] ts

    bias_kernel<<<(kB * kN + kN) / kR, 256, 0, stream>>>(all_ts, pos_w, ts_w, out);
}

// Round 8
// 49.917 us; speedup vs baseline: 1.1871x; 1.1871x over previous
//
#include <hip/hip_runtime.h>

// Problem constants (fixed by the reference).
constexpr int kN = 2048;
constexpr int kB = 16;
constexpr int kNB = 128;  // NUM_BUCKETS

// fl32(ln2) = 0x3F317218 — what any f32 log chain divides by (log(2.0f)).
#define LN2_BITS 0x3f317218u

// Native vector types (HIP's float4/int4 are classes; nontemporal builtin
// needs a true vector type).
typedef float f32x4 __attribute__((ext_vector_type(4)));
typedef int   i32x4 __attribute__((ext_vector_type(4)));

// ---------------------------------------------------------------------------
// Bucket matching the all-f32 arbiter chain with correctly-rounded f32 log
// (verified absmax 0.0 in R3/R5/R6/R7 — DO NOT TOUCH):
//   bk = clip( floorf( fl32( CRlog32(a) / fl32(ln2) ) ), 0, 128 ), a = max(|dt|,1)
// Fast path 31-clz(a) is provably identical outside narrow windows around 2^j;
// inside, emulate with (float)log((double)a) + IEEE f32 divide.
// ---------------------------------------------------------------------------
__device__ __forceinline__ int bucket_of(int rowts, int tj) {
    int dt = rowts - tj;
    unsigned a = (unsigned)(dt < 0 ? -dt : dt);
    a = a < 1u ? 1u : a;                   // a in [1, 10^7) < 2^24
    int k = 31 - __clz((int)a);            // exact floor(log2(a))
    unsigned p = 1u << k;
    unsigned Wlo = ((p >> 20) * (unsigned)k) + 8u;
    unsigned Whi = ((p >> 19) * (unsigned)(k + 1)) + 8u;
    bool danger = ((a - p) < Wlo) | (((p << 1) - a) < Whi);
    if (!danger) return k;
    float L = (float)log((double)a);       // correctly-rounded f32 log(a)
    float q = L / __uint_as_float(LN2_BITS);  // IEEE f32 divide (no fast-math)
    int bk = (int)floorf(q);
    return bk < 0 ? 0 : (bk > kNB ? kNB : bk);
}

// ---------------------------------------------------------------------------
// Fused kernel: one block per output row (uniform shape: 2048 floats = 2
// f32x4 stores per thread @ 256 threads). Verified fastest config (R5):
// one-row blocks beat 4-row blocks by 17% regardless of store order (R6/R7).
//   blocks [0, B*N)        : ts-bias row (b,i) of out[N*N + ...]
//   blocks [B*N, B*N + N)  : pos-bias row i of out[0 ...]
// Output is write-once and bigger than L3 -> nontemporal stores.
// ---------------------------------------------------------------------------
__global__ __launch_bounds__(256) void bias_kernel(const int* __restrict__ ts,
                                                   const float* __restrict__ pos_w,
                                                   const float* __restrict__ ts_w,
                                                   float* __restrict__ out) {
    const int blk = blockIdx.x;

    if (blk < kB * kN) {
        // ---- bucketized timestamp bias row ----
        __shared__ float w[kNB + 1];
        if (threadIdx.x <= kNB) w[threadIdx.x] = ts_w[threadIdx.x];
        __syncthreads();

        const int b = blk >> 11;            // / kN
        const int i = blk & (kN - 1);
        const int* __restrict__ tsrow = ts + (size_t)b * kN;
        const int rowts = tsrow[min(i + 1, kN - 1)];

        const i32x4* __restrict__ ts4 = (const i32x4*)tsrow;
        f32x4* __restrict__ orow4 =
            (f32x4*)(out + (size_t)kN * kN + (size_t)blk * kN);

        #pragma unroll
        for (int kk = 0; kk < kN / (4 * 256); ++kk) {
            const int v = kk * 256 + threadIdx.x;
            const i32x4 t4 = ts4[v];
            f32x4 r;
            r.x = w[bucket_of(rowts, t4.x)];
            r.y = w[bucket_of(rowts, t4.y)];
            r.z = w[bucket_of(rowts, t4.z)];
            r.w = w[bucket_of(rowts, t4.w)];
            __builtin_nontemporal_store(r, &orow4[v]);
        }
    } else {
        // ---- relative position bias row: out[i][j] = pos_w[N-1-i + j] ----
        const int i = blk - kB * kN;
        const float* __restrict__ src = pos_w + (kN - 1 - i);  // L1/L2-resident
        f32x4* __restrict__ orow4 = (f32x4*)(out + (size_t)i * kN);
        #pragma unroll
        for (int kk = 0; kk < kN / (4 * 256); ++kk) {
            const int v = kk * 256 + threadIdx.x;
            f32x4 r;
            r.x = src[4 * v + 0];
            r.y = src[4 * v + 1];
            r.z = src[4 * v + 2];
            r.w = src[4 * v + 3];
            __builtin_nontemporal_store(r, &orow4[v]);
        }
    }
}

extern "C" void kernel_launch(void* const* d_in, const int* in_sizes, int n_in,
                              void* d_out, int out_size, void* d_ws, size_t ws_size,
                              hipStream_t stream) {
    const int*   all_ts = (const int*)d_in[0];    // (B, N) int32
    const float* pos_w  = (const float*)d_in[1];  // (2N-1,) f32
    const float* ts_w   = (const float*)d_in[2];  // (NB+1,) f32
    float* out = (float*)d_out;                   // [N*N] pos ++ [B*N*N] ts

    bias_kernel<<<kB * kN + kN, 256, 0, stream>>>(all_ts, pos_w, ts_w, out);
}